// Round 10
// baseline (248.305 us; speedup 1.0000x reference)
//
#include <hip/hip_runtime.h>

#define E 16
#define HID 32
#define NSTEP 10
#define TAU 0.5f
#define SIGMA 0.5f
#define RES 0.5f
#define NT2 2         // 32-point tiles per wave (64 pts/wave)
#define STRIDE 36     // LDS row stride (floats): 144B, 16B-aligned

typedef __attribute__((ext_vector_type(8))) short bf16x8;
typedef __attribute__((ext_vector_type(16))) float f32x16;
typedef __attribute__((ext_vector_type(4))) unsigned int u32x4;

__device__ __forceinline__ f32x16 mfma32(bf16x8 a, bf16x8 b, f32x16 c) {
    return __builtin_amdgcn_mfma_f32_32x32x16_bf16(a, b, c, 0, 0, 0);
}
// one v_cvt_pk_bf16_f32: dst = {bf16(lo) , bf16(hi)<<16}
__device__ __forceinline__ unsigned int pk2(float lo, float hi) {
    unsigned int r;
    asm("v_cvt_pk_bf16_f32 %0, %1, %2" : "=v"(r) : "v"(lo), "v"(hi));
    return r;
}
// split 8 f32 -> hi/lo bf16x8; 3-term product AhBh+AhBl+AlBh is f32-equivalent.
// R8 lesson (recalibrated): in-loop split error gain ~260x (safe, R7=0.031);
// upstream-of-loop error gain ~3000x (R8's g-error 1e-4 -> 0.317 fail).
// Split-MFMA stays strictly in/adjacent-to the loop; encoder stays f32 scalar.
__device__ __forceinline__ void split8(const float v[8], bf16x8& hi, bf16x8& lo) {
    u32x4 H, L;
#pragma unroll
    for (int j = 0; j < 4; ++j) {
        const unsigned int h = pk2(v[2 * j], v[2 * j + 1]);
        H[j] = h;
        const float h0 = __uint_as_float(h << 16);
        const float h1 = __uint_as_float(h & 0xffff0000u);
        L[j] = pk2(v[2 * j] - h0, v[2 * j + 1] - h1);
    }
    hi = __builtin_bit_cast(bf16x8, H);
    lo = __builtin_bit_cast(bf16x8, L);
}

__device__ __forceinline__ float fast_tanh(float v) {
    float e = __expf(2.0f * v);
    return 1.0f - __fdividef(2.0f, e + 1.0f);
}
__device__ __forceinline__ float inv_norm_clamped(float n2) {
    return fminf(__builtin_amdgcn_rsqf(n2), 1.0f);
}
// pair-sum across kh groups (lane ^ 32): 1 shuffle vs 16x16's 2-hop bsum4
__device__ __forceinline__ float bsum2(float x) { return x + __shfl_xor(x, 32); }

// waves_per_eu(2,3): budget 256 VGPR — the R1/R6 catastrophic spill cliff is
// unreachable; worst case 2 waves/EU, and R2-R9 proved occupancy insensitivity.
// 32x32 shape: scalar replication 4x->2x, bsum4->bsum2 — ~660 fewer inst/wave.
__global__ __attribute__((amdgpu_waves_per_eu(2, 3))) __launch_bounds__(256)
void pdhg_kernel(
    const float* __restrict__ xg,  const float* __restrict__ Gg,  const float* __restrict__ hg,
    const float* __restrict__ W1,  const float* __restrict__ b1,
    const float* __restrict__ W2,  const float* __restrict__ b2,
    const float* __restrict__ Wmu, const float* __restrict__ bmu,
    const float* __restrict__ Wy,  const float* __restrict__ by,
    const float* __restrict__ Wp1, const float* __restrict__ bp1,
    const float* __restrict__ Wp2, const float* __restrict__ bp2,
    float* __restrict__ out, int npts)
{
    __shared__ __align__(16) float sT[256 * STRIDE];
    const int tid = threadIdx.x;

    // ============ scalar phase: encoder L1+L2 (f32), one point per thread ============
    {
        const int pt = blockIdx.x * 256 + tid;
        const int ptc = min(pt, npts - 1);     // clamp; no early return (barrier below)
        const float2 xv = reinterpret_cast<const float2*>(xg)[ptc];
        const float x0 = xv.x, x1 = xv.y;

        float g[HID];
        #pragma unroll
        for (int j = 0; j < HID; ++j) g[j] = b2[j];
        #pragma unroll
        for (int ci = 0; ci < 4; ++ci) {
            float fc[8];
            #pragma unroll
            for (int jj = 0; jj < 8; ++jj) {
                const int j = ci * 8 + jj;
                fc[jj] = fmaxf(fmaf(x0, W1[j], fmaf(x1, W1[HID + j], b1[j])), 0.0f);
            }
            #pragma unroll
            for (int ii = 0; ii < 8; ++ii) {
                const int i = ci * 8 + ii;
                #pragma unroll
                for (int j = 0; j < HID; ++j) g[j] = fmaf(fc[ii], W2[i * HID + j], g[j]);
            }
        }
        float* row = sT + tid * STRIDE;
        row[0] = x0; row[1] = x1;
        #pragma unroll
        for (int jq = 0; jq < 8; ++jq) {
            const int j = jq * 4;
            reinterpret_cast<float4*>(row + 4)[jq] = make_float4(
                fmaxf(g[j], 0.f), fmaxf(g[j + 1], 0.f),
                fmaxf(g[j + 2], 0.f), fmaxf(g[j + 3], 0.f));
        }
    }
    __syncthreads();

    // ============ 32x32 MFMA-layout phase ============
    // C/D (m74/m101): col = lane&31 (point), row = (reg&3)+8*(reg>>2)+4*(lane>>5),
    // reg 0..7 covers rows 0..15 = E; regs 8..15 (rows 16..31) forced to 0 via
    // zeroed A rows (col>=16). A/B slot->k map per K-window: kh*8+i (shared).
    const int lane = tid & 63;
    const int col  = lane & 31;
    const int kh   = lane >> 5;
    const bool colOK = col < E;
    const int colc = colOK ? col : 0;      // clamped addr; value zeroed by select
    const int pbase = blockIdx.x * 256 + (tid >> 6) * 64;

    // per-lane row constants (rows e(r,kh)) + C-init with bp2 rows
    float gxr[8], gyr[8], thr8[8];
    f32x16 cinit;
    #pragma unroll
    for (int r = 0; r < 8; ++r) {
        const int e = (r & 3) + 8 * (r >> 2) + 4 * kh;
        gxr[r] = Gg[2 * e];
        gyr[r] = Gg[2 * e + 1];
        thr8[r] = TAU * hg[e];
        cinit[r] = bp2[e];
    }
    #pragma unroll
    for (int r = 8; r < 16; ++r) cinit[r] = 0.0f;

    float tg00, tg01, tg11;
    {
        float s00 = 0.f, s01 = 0.f, s11 = 0.f;
        #pragma unroll
        for (int r = 0; r < 8; ++r) {
            s00 = fmaf(gxr[r], gxr[r], s00);
            s01 = fmaf(gxr[r], gyr[r], s01);
            s11 = fmaf(gyr[r], gyr[r], s11);
        }
        tg00 = TAU * bsum2(s00);
        tg01 = TAU * bsum2(s01);
        tg11 = TAU * bsum2(s11);
    }

    // Wp2 A-frags per K-window (VGPR-resident)
    bf16x8 wp2h[2], wp2l[2];
    #pragma unroll
    for (int w = 0; w < 2; ++w) {
        float wv[8];
        #pragma unroll
        for (int i = 0; i < 8; ++i) {
            const int k = w * 16 + kh * 8 + i;
            wv[i] = colOK ? Wp2[k * E + colc] : 0.0f;
        }
        split8(wv, wp2h[w], wp2l[w]);
    }
    // Wp1 per-lane k-slices (16 k per lane across 2 windows)
    float wp1a[16], wp1b[16], bp1r[16];
    #pragma unroll
    for (int w = 0; w < 2; ++w)
        #pragma unroll
        for (int i = 0; i < 8; ++i) {
            const int k = w * 16 + kh * 8 + i;
            wp1a[w * 8 + i] = Wp1[k];
            wp1b[w * 8 + i] = Wp1[HID + k];
            bp1r[w * 8 + i] = bp1[k];
        }

    float mu[NT2][8];
    float y0[NT2], y1[NT2], v0[NT2], v1[NT2], tc0[NT2], tc1[NT2];
    float tpx0[NT2], tpx1[NT2];

    // ---------------- heads (transient constants; freed before the loop) --------
    {
        bf16x8 wmuh[2], wmul[2];
        #pragma unroll
        for (int w = 0; w < 2; ++w) {
            float wv[8];
            #pragma unroll
            for (int i = 0; i < 8; ++i) {
                const int k = w * 16 + kh * 8 + i;
                wv[i] = colOK ? Wmu[k * E + colc] : 0.0f;
            }
            split8(wv, wmuh[w], wmul[w]);
        }
        float wya[16], wyb[16];
        #pragma unroll
        for (int w = 0; w < 2; ++w)
            #pragma unroll
            for (int i = 0; i < 8; ++i) {
                const int k = w * 16 + kh * 8 + i;
                wya[w * 8 + i] = Wy[k * 2];
                wyb[w * 8 + i] = Wy[k * 2 + 1];
            }
        f32x16 cinitH;
        #pragma unroll
        for (int r = 0; r < 8; ++r)
            cinitH[r] = bmu[(r & 3) + 8 * (r >> 2) + 4 * kh];
        #pragma unroll
        for (int r = 8; r < 16; ++r) cinitH[r] = 0.0f;
        const float by0 = by[0], by1 = by[1];

        #pragma unroll
        for (int t = 0; t < NT2; ++t) {
            const float* prow = sT + (size_t)((tid >> 6) * 64 + t * 32 + col) * STRIDE;
            const float4* p4 = reinterpret_cast<const float4*>(prow);
            float gA[8], gB[8];
            {
                const float4 a0 = p4[1 + 2 * kh], a1 = p4[2 + 2 * kh];
                const float4 b0 = p4[5 + 2 * kh], b1v = p4[6 + 2 * kh];
                gA[0]=a0.x; gA[1]=a0.y; gA[2]=a0.z; gA[3]=a0.w;
                gA[4]=a1.x; gA[5]=a1.y; gA[6]=a1.z; gA[7]=a1.w;
                gB[0]=b0.x; gB[1]=b0.y; gB[2]=b0.z; gB[3]=b0.w;
                gB[4]=b1v.x; gB[5]=b1v.y; gB[6]=b1v.z; gB[7]=b1v.w;
            }
            const float px0 = prow[0], px1 = prow[1];
            // y head: per-lane partials over 16 k-slots + bsum2 over kh
            float p0 = 0.f, p1 = 0.f;
            #pragma unroll
            for (int i = 0; i < 8; ++i) {
                p0 = fmaf(gA[i], wya[i], p0);      p1 = fmaf(gA[i], wyb[i], p1);
                p0 = fmaf(gB[i], wya[8 + i], p0);  p1 = fmaf(gB[i], wyb[8 + i], p1);
            }
            y0[t] = fast_tanh(by0 + bsum2(p0));
            y1[t] = fast_tanh(by1 + bsum2(p1));
            // mu head: 2 windows x 3-term split chain, C = bmu rows
            bf16x8 ghA, glA, ghB, glB;
            split8(gA, ghA, glA);
            split8(gB, ghB, glB);
            f32x16 d = mfma32(wmul[0], ghA, cinitH);
            d = mfma32(wmuh[0], glA, d);
            d = mfma32(wmuh[0], ghA, d);
            d = mfma32(wmul[1], ghB, d);
            d = mfma32(wmuh[1], glB, d);
            d = mfma32(wmuh[1], ghB, d);
            float q0 = 0.f, q1 = 0.f, r0 = 0.f, r1 = 0.f;
            #pragma unroll
            for (int r = 0; r < 8; ++r) {
                const float m = fmaxf(d[r], 0.0f);
                mu[t][r] = m;
                // ta = TAU*(px.G - h) = fma(TAU, px.G, -TAU*h)
                const float tae = fmaf(TAU, fmaf(px0, gxr[r], px1 * gyr[r]), -thr8[r]);
                q0 = fmaf(tae, gxr[r], q0);
                q1 = fmaf(tae, gyr[r], q1);
                r0 = fmaf(m, gxr[r], r0);
                r1 = fmaf(m, gyr[r], r1);
            }
            tc0[t] = bsum2(q0); tc1[t] = bsum2(q1);
            v0[t]  = bsum2(r0); v1[t]  = bsum2(r1);
            tpx0[t] = TAU * px0; tpx1[t] = TAU * px1;
        }
    }

    // ---------------- PDHG steps ----------------
    #pragma unroll 1
    for (int s = 0; s < NSTEP; ++s) {
        #pragma unroll
        for (int t = 0; t < NT2; ++t) {
            // y += SIGMA*v; unit-ball project (x2 kh redundancy, was x4)
            float a0 = fmaf(SIGMA, v0[t], y0[t]);
            float a1 = fmaf(SIGMA, v1[t], y1[t]);
            const float sc = inv_norm_clamped(fmaf(a0, a0, a1 * a1));
            a0 *= sc; a1 *= sc;
            y0[t] = a0; y1[t] = a1;
            // z = v + tc - TAU*GtG@y
            const float z0 = fmaf(-tg00, a0, fmaf(-tg01, a1, v0[t] + tc0[t]));
            const float z1 = fmaf(-tg01, a0, fmaf(-tg11, a1, v1[t] + tc1[t]));
            // mu += ta - TAU*y@G^T == (mu - TAU*h) + u0*gx + u1*gy, u = TAU*(px-y)
            const float u0 = fmaf(-TAU, a0, tpx0[t]);
            const float u1 = fmaf(-TAU, a1, tpx1[t]);
            #pragma unroll
            for (int r = 0; r < 8; ++r)
                mu[t][r] = fmaf(u1, gyr[r], fmaf(u0, gxr[r], mu[t][r] - thr8[r]));

            // prox: hk per K-window (f32) -> split -> 3-term MFMA chain
            f32x16 d;
            {
                float hk[8];
                #pragma unroll
                for (int i = 0; i < 8; ++i)
                    hk[i] = fmaxf(fmaf(z0, wp1a[i], fmaf(z1, wp1b[i], bp1r[i])), 0.0f);
                bf16x8 bh, bl;
                split8(hk, bh, bl);
                d = mfma32(wp2l[0], bh, cinit);
                d = mfma32(wp2h[0], bl, d);
                d = mfma32(wp2h[0], bh, d);
            }
            {
                float hk[8];
                #pragma unroll
                for (int i = 0; i < 8; ++i)
                    hk[i] = fmaxf(fmaf(z0, wp1a[8 + i], fmaf(z1, wp1b[8 + i], bp1r[8 + i])), 0.0f);
                bf16x8 bh, bl;
                split8(hk, bh, bl);
                d = mfma32(wp2l[1], bh, d);
                d = mfma32(wp2h[1], bl, d);
                d = mfma32(wp2h[1], bh, d);
            }

            // mu = project(mu + RES*dl); maintain v
            float p0 = 0.f, p1 = 0.f;
            #pragma unroll
            for (int r = 0; r < 8; ++r) {
                const float m = fmaxf(fmaf(RES, d[r], mu[t][r]), 0.0f);
                mu[t][r] = m;
                p0 = fmaf(m, gxr[r], p0);
                p1 = fmaf(m, gyr[r], p1);
            }
            p0 = bsum2(p0); p1 = bsum2(p1);
            const float sp = inv_norm_clamped(fmaf(p0, p0, p1 * p1));
            #pragma unroll
            for (int r = 0; r < 8; ++r) mu[t][r] *= sp;
            v0[t] = sp * p0;
            v1[t] = sp * p1;
        }
    }

    // ---------------- store: rows {0-3,8-11}+4kh -> two float4 per tile ---------
    #pragma unroll
    for (int t = 0; t < NT2; ++t) {
        const int q = pbase + t * 32 + col;
        if (q < npts) {
            float* o = out + (size_t)q * E;
            *reinterpret_cast<float4*>(o + 4 * kh) =
                make_float4(mu[t][0], mu[t][1], mu[t][2], mu[t][3]);
            *reinterpret_cast<float4*>(o + 8 + 4 * kh) =
                make_float4(mu[t][4], mu[t][5], mu[t][6], mu[t][7]);
        }
    }
}

extern "C" void kernel_launch(void* const* d_in, const int* in_sizes, int n_in,
                              void* d_out, int out_size, void* d_ws, size_t ws_size,
                              hipStream_t stream) {
    const float* x   = (const float*)d_in[0];
    const float* G   = (const float*)d_in[1];
    const float* h   = (const float*)d_in[2];
    const float* W1  = (const float*)d_in[3];
    const float* b1  = (const float*)d_in[4];
    const float* W2  = (const float*)d_in[5];
    const float* b2  = (const float*)d_in[6];
    const float* Wmu = (const float*)d_in[7];
    const float* bmu = (const float*)d_in[8];
    const float* Wy  = (const float*)d_in[9];
    const float* by  = (const float*)d_in[10];
    const float* Wp1 = (const float*)d_in[11];
    const float* bp1 = (const float*)d_in[12];
    const float* Wp2 = (const float*)d_in[13];
    const float* bp2 = (const float*)d_in[14];

    const int npts = in_sizes[0] / 2;   // x is [N,2]
    const int block = 256;              // 256 points per block
    const int grid = (npts + block - 1) / block;

    pdhg_kernel<<<grid, block, 0, stream>>>(x, G, h, W1, b1, W2, b2, Wmu, bmu,
                                            Wy, by, Wp1, bp1, Wp2, bp2,
                                            (float*)d_out, npts);
}